// Round 7
// baseline (311.600 us; speedup 1.0000x reference)
//
#include <hip/hip_runtime.h>

typedef __attribute__((ext_vector_type(4))) float    f32x4;
typedef __attribute__((ext_vector_type(4))) unsigned u32x4;
typedef __attribute__((ext_vector_type(8))) short    s16x8;

#define LOG2E 1.44269504088896340736f
__device__ __forceinline__ float fexp2(float x){ return __builtin_amdgcn_exp2f(x); }
__device__ __forceinline__ float frcp (float x){ return __builtin_amdgcn_rcpf(x); }
__device__ __forceinline__ float sigf (float x){ return frcp(1.0f + fexp2(-LOG2E*x)); }
__device__ __forceinline__ float tanh_(float x){ return 1.0f - 2.0f*frcp(1.0f + fexp2(2.0f*LOG2E*x)); }

// builtin MFMA: compiler models operand hazards (inline-asm MFMA does NOT —
// VALU->MFMA-read wait-states were the R5/R6 corruption source)
__device__ __forceinline__ f32x4 mfma16(u32x4 a, u32x4 b, f32x4 c){
    return __builtin_amdgcn_mfma_f32_16x16x32_bf16(
        __builtin_bit_cast(s16x8, a), __builtin_bit_cast(s16x8, b), c, 0, 0, 0);
}

// round-to-nearest-even fp32 -> bf16 (low 16 bits)
__device__ __forceinline__ unsigned rne_bf16(float f){
    unsigned u = __builtin_bit_cast(unsigned, f);
    return (u + 0x7fffu + ((u >> 16) & 1u)) >> 16;
}
// hi weight word: rne(w) duplicated in both bf16 slots
__device__ __forceinline__ u32x4 packdup4(const float* p){
    u32x4 r;
    #pragma unroll
    for (int q = 0; q < 4; ++q) {
        unsigned w = rne_bf16(p[q]);
        r[q] = w | (w << 16);
    }
    return r;
}
// lo weight word: rne(w - hi) duplicated — twin chain restores fp32 weight precision
__device__ __forceinline__ u32x4 packdup4_lo(const float* p){
    u32x4 r;
    #pragma unroll
    for (int q = 0; q < 4; ++q) {
        unsigned wh = rne_bf16(p[q]);
        float    wf = __builtin_bit_cast(float, wh << 16);
        unsigned wl = rne_bf16(p[q] - wf);
        r[q] = wl | (wl << 16);
    }
    return r;
}
// value word: lo half = bf16_trunc(h), hi half = bf16_trunc(h - hi)
__device__ __forceinline__ unsigned packsplit(float h){
    unsigned hu = __builtin_bit_cast(unsigned, h);
    unsigned hm = hu & 0xffff0000u;
    float rem = h - __builtin_bit_cast(float, hm);
    unsigned ru = __builtin_bit_cast(unsigned, rem);
    return (hm >> 16) | (ru & 0xffff0000u);
}

// B=4096, I=8, T=512, H1=32, H2=16, O=1.
// 16 seqs per block, 256 blocks (1/CU). 3 waves: w0/w1 = layer1 units
// 0..15/16..31, w2 = layer2 (lagging 1 step).
// Precision: weights split hi+lo bf16 (twin MFMA chains, parallel accs);
// values split hi/lo within each k-word. Own state half stays in registers
// (C-row == B-k-word identity, proven by R4); h2 feedback fully in-register.
__global__ __launch_bounds__(192)
void gru2_mfma(const float* __restrict__ x_g,
               const float* __restrict__ Wih1, const float* __restrict__ Whh1,
               const float* __restrict__ bih1, const float* __restrict__ bhh1,
               const float* __restrict__ Wih2, const float* __restrict__ Whh2,
               const float* __restrict__ bih2, const float* __restrict__ bhh2,
               const float* __restrict__ Wlin, const float* __restrict__ blin,
               float* __restrict__ out)
{
    const int tid = threadIdx.x;
    const int wid = tid / 64;
    const int l   = tid & 63;
    const int sl  = l & 15;   // seq (MFMA col); also C col
    const int g   = l >> 4;   // k/row group
    const int b0  = blockIdx.x * 16;

    __shared__ unsigned xpk[32][16][12];  // [t][seq][8 x-words + pad4]
    __shared__ unsigned h1b[2][16][36];   // [par][seq][32 unit-words + pad4]
    __shared__ unsigned zl[4];            // zeros for T0 k>=16

    {
        unsigned* p1 = &h1b[0][0][0];
        for (int k = tid; k < 2*16*36; k += 192) p1[k] = 0u;
        if (tid < 4) zl[tid] = 0u;
    }

    // ---------------- per-role weight + bias fragments (hi + lo twins) ----
    u32x4 fR0,fR0l, fR1,fR1l, fR2,fR2l, fZ0,fZ0l, fZ1,fZ1l, fZ2,fZ2l,
          fX0,fX0l, fA,fAl, fB,fBl;
    f32x4 cbR, cbZ, cbX, cbH;
    const u32x4 zero4 = {0u,0u,0u,0u};

    if (wid < 2) {
        const int Ub = wid * 16;
        const int gr = Ub + sl, gz = 32 + Ub + sl, gn = 64 + Ub + sl;
        fR0  = (g < 2) ? packdup4   (Wih1 + gr*8 + 4*g) : zero4;
        fR0l = (g < 2) ? packdup4_lo(Wih1 + gr*8 + 4*g) : zero4;
        fR1  = packdup4   (Whh1 + gr*32 + 4*g);
        fR1l = packdup4_lo(Whh1 + gr*32 + 4*g);
        fR2  = packdup4   (Whh1 + gr*32 + 16 + 4*g);
        fR2l = packdup4_lo(Whh1 + gr*32 + 16 + 4*g);
        fZ0  = (g < 2) ? packdup4   (Wih1 + gz*8 + 4*g) : zero4;
        fZ0l = (g < 2) ? packdup4_lo(Wih1 + gz*8 + 4*g) : zero4;
        fZ1  = packdup4   (Whh1 + gz*32 + 4*g);
        fZ1l = packdup4_lo(Whh1 + gz*32 + 4*g);
        fZ2  = packdup4   (Whh1 + gz*32 + 16 + 4*g);
        fZ2l = packdup4_lo(Whh1 + gz*32 + 16 + 4*g);
        fX0  = (g < 2) ? packdup4   (Wih1 + gn*8 + 4*g) : zero4;
        fX0l = (g < 2) ? packdup4_lo(Wih1 + gn*8 + 4*g) : zero4;
        fA   = packdup4   (Whh1 + gn*32 + 4*g);
        fAl  = packdup4_lo(Whh1 + gn*32 + 4*g);
        fB   = packdup4   (Whh1 + gn*32 + 16 + 4*g);
        fBl  = packdup4_lo(Whh1 + gn*32 + 16 + 4*g);
        #pragma unroll
        for (int e = 0; e < 4; ++e) {
            const int u = Ub + 4*g + e;
            cbR[e] = bih1[u]      + bhh1[u];
            cbZ[e] = bih1[32+u]   + bhh1[32+u];
            cbX[e] = bih1[64+u];
            cbH[e] = bhh1[64+u];
        }
    } else {
        fR0  = packdup4   (Wih2 + sl*32 + 4*g);
        fR0l = packdup4_lo(Wih2 + sl*32 + 4*g);
        fR1  = packdup4   (Wih2 + sl*32 + 16 + 4*g);
        fR1l = packdup4_lo(Wih2 + sl*32 + 16 + 4*g);
        fR2  = packdup4   (Whh2 + sl*16 + 4*g);
        fR2l = packdup4_lo(Whh2 + sl*16 + 4*g);
        fZ0  = packdup4   (Wih2 + (16+sl)*32 + 4*g);
        fZ0l = packdup4_lo(Wih2 + (16+sl)*32 + 4*g);
        fZ1  = packdup4   (Wih2 + (16+sl)*32 + 16 + 4*g);
        fZ1l = packdup4_lo(Wih2 + (16+sl)*32 + 16 + 4*g);
        fZ2  = packdup4   (Whh2 + (16+sl)*16 + 4*g);
        fZ2l = packdup4_lo(Whh2 + (16+sl)*16 + 4*g);
        fX0  = packdup4   (Wih2 + (32+sl)*32 + 4*g);
        fX0l = packdup4_lo(Wih2 + (32+sl)*32 + 4*g);
        fA   = packdup4   (Wih2 + (32+sl)*32 + 16 + 4*g);
        fAl  = packdup4_lo(Wih2 + (32+sl)*32 + 16 + 4*g);
        fB   = packdup4   (Whh2 + (32+sl)*16 + 4*g);
        fBl  = packdup4_lo(Whh2 + (32+sl)*16 + 4*g);
        #pragma unroll
        for (int e = 0; e < 4; ++e) {
            const int u = 4*g + e;
            cbR[e] = bih2[u]    + bhh2[u];
            cbZ[e] = bih2[16+u] + bhh2[16+u];
            cbX[e] = bih2[32+u];
            cbH[e] = bhh2[32+u];
        }
    }

    float hv[4] = {0.f,0.f,0.f,0.f};   // fp32 state (w0/w1: h1 half; w2: h2)
    u32x4 own   = {0u,0u,0u,0u};       // packed own-state B-operand
    const f32x4 zc = {0.f,0.f,0.f,0.f};

    #pragma unroll 1
    for (int i = 0; i <= 512; ++i) {
        if ((i & 31) == 0 && i < 512) {
            // stage 32 timesteps of x, pre-split to bf16 hi/lo words
            if (tid < 128) {
                const int s  = tid >> 3;
                const int ii = tid & 7;
                const float* xg = x_g + ((size_t)(b0 + s))*4096 + ii*512 + i;
                #pragma unroll
                for (int w4 = 0; w4 < 8; ++w4) {
                    const f32x4 v = *(const f32x4*)(xg + 4*w4);
                    #pragma unroll
                    for (int e = 0; e < 4; ++e)
                        xpk[w4*4 + e][s][ii] = packsplit(v[e]);
                }
            }
            __syncthreads();
        }

        const int pr = (i + 1) & 1;   // parity holding h1(i-1)

        if (wid < 2 && i < 512) {
            const int tt = i & 31;
            const u32x4 bT0 = (g < 2) ? *(const u32x4*)&xpk[tt][sl][4*g]
                                      : *(const u32x4*)&zl[0];
            u32x4 bT1, bT2;
            if (wid == 0) { bT1 = own;
                            bT2 = *(const u32x4*)&h1b[pr][sl][16 + 4*g]; }
            else          { bT1 = *(const u32x4*)&h1b[pr][sl][4*g];
                            bT2 = own; }
            f32x4 crh, crl, czh, czl, cx, cnh, cnl;
            crh = mfma16(fR0,  bT0, cbR); crh = mfma16(fR1,  bT1, crh); crh = mfma16(fR2,  bT2, crh);
            crl = mfma16(fR0l, bT0, zc ); crl = mfma16(fR1l, bT1, crl); crl = mfma16(fR2l, bT2, crl);
            czh = mfma16(fZ0,  bT0, cbZ); czh = mfma16(fZ1,  bT1, czh); czh = mfma16(fZ2,  bT2, czh);
            czl = mfma16(fZ0l, bT0, zc ); czl = mfma16(fZ1l, bT1, czl); czl = mfma16(fZ2l, bT2, czl);
            cx  = mfma16(fX0,  bT0, cbX); cx  = mfma16(fX0l, bT0, cx );
            cnh = mfma16(fA,   bT1, cbH); cnh = mfma16(fB,   bT2, cnh);
            cnl = mfma16(fAl,  bT1, zc ); cnl = mfma16(fBl,  bT2, cnl);
            #pragma unroll
            for (int e = 0; e < 4; ++e) {
                const float r = sigf(crh[e] + crl[e]);
                const float z = sigf(czh[e] + czl[e]);
                const float n = tanh_(fmaf(r, cnh[e] + cnl[e], cx[e]));
                const float h = n + z*(hv[e] - n);
                hv[e] = h;
                own[e] = packsplit(h);
            }
            *(u32x4*)&h1b[i & 1][sl][(wid ? 16 : 0) + 4*g] = own;
        }

        if (wid == 2 && i > 0) {
            const u32x4 bU0 = *(const u32x4*)&h1b[pr][sl][4*g];
            const u32x4 bU1 = *(const u32x4*)&h1b[pr][sl][16 + 4*g];
            const u32x4 bU2 = own;                 // h2(i-2), in-register
            f32x4 crh, crl, czh, czl, cx, cn;
            crh = mfma16(fR0,  bU0, cbR); crh = mfma16(fR1,  bU1, crh); crh = mfma16(fR2,  bU2, crh);
            crl = mfma16(fR0l, bU0, zc ); crl = mfma16(fR1l, bU1, crl); crl = mfma16(fR2l, bU2, crl);
            czh = mfma16(fZ0,  bU0, cbZ); czh = mfma16(fZ1,  bU1, czh); czh = mfma16(fZ2,  bU2, czh);
            czl = mfma16(fZ0l, bU0, zc ); czl = mfma16(fZ1l, bU1, czl); czl = mfma16(fZ2l, bU2, czl);
            cx  = mfma16(fX0,  bU0, cbX); cx  = mfma16(fA,   bU1, cx );
            cx  = mfma16(fX0l, bU0, cx ); cx  = mfma16(fAl,  bU1, cx );
            cn  = mfma16(fB,   bU2, cbH); cn  = mfma16(fBl,  bU2, cn );
            #pragma unroll
            for (int e = 0; e < 4; ++e) {
                const float r = sigf(crh[e] + crl[e]);
                const float z = sigf(czh[e] + czl[e]);
                const float n = tanh_(fmaf(r, cn[e], cx[e]));
                const float h = n + z*(hv[e] - n);
                hv[e] = h;
                own[e] = packsplit(h);
            }
        }

        __syncthreads();
    }

    // -------- linear head: w2's hv = fp32 h2(T-1) for units 4g..4g+3 ------
    if (wid == 2) {
        float acc = 0.0f;
        acc = fmaf(Wlin[4*g+0], hv[0], acc);
        acc = fmaf(Wlin[4*g+1], hv[1], acc);
        acc = fmaf(Wlin[4*g+2], hv[2], acc);
        acc = fmaf(Wlin[4*g+3], hv[3], acc);
        acc += __shfl_xor(acc, 16, 64);
        acc += __shfl_xor(acc, 32, 64);
        if (g == 0) out[b0 + sl] = acc + blin[0];
    }
}

extern "C" void kernel_launch(void* const* d_in, const int* in_sizes, int n_in,
                              void* d_out, int out_size, void* d_ws, size_t ws_size,
                              hipStream_t stream) {
    const float* x    = (const float*)d_in[0];
    const float* Wih1 = (const float*)d_in[1];
    const float* Whh1 = (const float*)d_in[2];
    const float* bih1 = (const float*)d_in[3];
    const float* bhh1 = (const float*)d_in[4];
    const float* Wih2 = (const float*)d_in[5];
    const float* Whh2 = (const float*)d_in[6];
    const float* bih2 = (const float*)d_in[7];
    const float* bhh2 = (const float*)d_in[8];
    const float* Wlin = (const float*)d_in[9];
    const float* blin = (const float*)d_in[10];
    float* out = (float*)d_out;

    dim3 grid(256), block(192);
    hipLaunchKernelGGL(gru2_mfma, grid, block, 0, stream,
                       x, Wih1, Whh1, bih1, bhh1, Wih2, Whh2, bih2, bhh2,
                       Wlin, blin, out);
}